// Round 15
// baseline (165.024 us; speedup 1.0000x reference)
//
#include <hip/hip_runtime.h>

typedef unsigned short u16;
typedef unsigned int u32;
typedef __bf16 bf16x8 __attribute__((ext_vector_type(8)));
typedef float f32x4 __attribute__((ext_vector_type(4)));
typedef unsigned short u16x4 __attribute__((ext_vector_type(4)));

#define LOG2E 1.4426950408889634f

#if __has_builtin(__builtin_amdgcn_exp2f)
#define EXP2F(x) __builtin_amdgcn_exp2f(x)
#else
#define EXP2F(x) exp2f(x)
#endif

__device__ __forceinline__ u16 f2bf(float f) {
    union { float f; u32 u; } a; a.f = f;
    u32 u = a.u;
    u += 0x7FFFu + ((u >> 16) & 1u);   // RNE (finite inputs)
    return (u16)(u >> 16);
}
__device__ __forceinline__ bf16x8 ldg8(const u16* p) {
    return *reinterpret_cast<const bf16x8*>(p);
}
#if __has_builtin(__builtin_amdgcn_cvt_pk_bf16_f32)
__device__ __forceinline__ u32 pack2(float a, float b) {
    auto r = __builtin_amdgcn_cvt_pk_bf16_f32(a, b);
    return __builtin_bit_cast(u32, r);
}
#else
__device__ __forceinline__ u32 pack2(float a, float b) {
    u32 ua = __float_as_uint(a) + 0x8000u;
    u32 ub = __float_as_uint(b) + 0x8000u;
    return __builtin_amdgcn_perm(ub, ua, 0x07060302);
}
#endif
__device__ __forceinline__ void async16(const void* g, void* l) {
    __builtin_amdgcn_global_load_lds(
        (const __attribute__((address_space(1))) u32*)g,
        (__attribute__((address_space(3))) u32*)l, 16, 0, 0);
}

#define MFMA16(a, b, c) __builtin_amdgcn_mfma_f32_16x16x32_bf16((a), (b), (c), 0, 0, 0)

// ---------------------------------------------------------------------------
// Fused prep: y<8 -> transpose X tile; y in 8..11 -> pack weight matrix;
// y==12 -> lqw * log2(e) into global fp32 (4 blocks). Grid (64, 13).
// ---------------------------------------------------------------------------
__global__ __launch_bounds__(256) void prep(const float* __restrict__ X,
                                            u16* __restrict__ Xt,
                                            const float* __restrict__ s0,
                                            const float* __restrict__ s1,
                                            const float* __restrict__ s2,
                                            const float* __restrict__ s3,
                                            u16* __restrict__ Wqkv,
                                            u16* __restrict__ Wp,
                                            const float* __restrict__ lqw,
                                            float* __restrict__ lqw2g) {
    __shared__ u16 tile[64][65];
    const int tid = threadIdx.x;
    const int y = blockIdx.y;

    if (y < 8) {                                  // transpose 64x64 tile
        const int t0 = blockIdx.x * 64;
        const int c0 = y * 64;
#pragma unroll
        for (int i = 0; i < 16; ++i) {
            int idx = tid + i * 256;
            int r = idx >> 6, cc = idx & 63;
            tile[r][cc] = f2bf(X[(size_t)(c0 + r) * 4096 + t0 + cc]);
        }
        __syncthreads();
#pragma unroll
        for (int i = 0; i < 16; ++i) {
            int idx = tid + i * 256;
            int tr = idx >> 6, cc = idx & 63;
            Xt[(size_t)(t0 + tr) * 512 + c0 + cc] = tile[cc][tr];
        }
    } else if (y < 12) {                          // pack one 512x512 weight
        const int m = y - 8;
        const float* s = (m == 0) ? s0 : (m == 1) ? s1 : (m == 2) ? s2 : s3;
        u16* d = (m == 3) ? Wp : Wqkv + (size_t)m * 262144;
#pragma unroll
        for (int j = 0; j < 4; ++j) {
            int i = blockIdx.x * 1024 + j * 256 + tid;
            float4 v = reinterpret_cast<const float4*>(s)[i];
            u16x4 o;
            o[0] = f2bf(v.x); o[1] = f2bf(v.y); o[2] = f2bf(v.z); o[3] = f2bf(v.w);
            reinterpret_cast<u16x4*>(d)[i] = o;
        }
    } else {                                      // lqw * LOG2E (1024 float4)
        if (blockIdx.x < 4) {
            int i = blockIdx.x * 256 + tid;
            float4 v = reinterpret_cast<const float4*>(lqw)[i];
            v.x *= LOG2E; v.y *= LOG2E; v.z *= LOG2E; v.w *= LOG2E;
            reinterpret_cast<float4*>(lqw2g)[i] = v;
        }
    }
}

// ---------------------------------------------------------------------------
// Fused QKV GEMM, BARRIER-FREE K-loop. B tile (64 tokens x 512 ch, 64 KB)
// staged to LDS ONCE (row-XOR swizzle at the async16 source); A (weight
// rows, contiguous, L2-resident) streamed from global directly into
// fragments. 16 unrolled K-steps with no barriers -> compiler pipelines
// all loads/MFMAs freely (vs 16 barrier-drain serializations before).
// 256 threads (4 waves), tile 128(M) x 64(N). Grid (64,12) = 768 blocks.
// ---------------------------------------------------------------------------
__global__ __launch_bounds__(256, 2) void qkv_gemm(const u16* __restrict__ Wqkv,
                                                   const u16* __restrict__ Xt,
                                                   const float* __restrict__ qb,
                                                   const float* __restrict__ kb,
                                                   const float* __restrict__ vb,
                                                   u16* __restrict__ Qt,
                                                   u16* __restrict__ Kt,
                                                   u16* __restrict__ Vp) {
    __shared__ __align__(16) u16 Bl[64 * 512];      // 64 KB, row r at byte r*1024

    const int tid = threadIdx.x;
    const int w = tid >> 6, lane = tid & 63;
    const int quad = lane >> 4, lm = lane & 15;
    const int wm = w & 1, wn = w >> 1;
    const int n0 = blockIdx.x * 64;
    const int my = blockIdx.y;                      // 0..11 over M=1536
    const int m0 = my * 128;

    // stage B once: wave w stages rows w+4j; lane supplies stored chunk
    // `lane`, source chunk lane^(r&7) (2-way-free fragment reads later).
#pragma unroll
    for (int j = 0; j < 16; ++j) {
        int r = w + j * 4;
        async16(Xt + (size_t)(n0 + r) * 512 + (lane ^ (r & 7)) * 8,
                (char*)Bl + r * 1024);
    }

    const u16* arow = Wqkv + (size_t)(m0 + wm * 64 + lm) * 512 + quad * 8;

    f32x4 acc[4][2];
#pragma unroll
    for (int mt = 0; mt < 4; ++mt)
#pragma unroll
        for (int bt = 0; bt < 2; ++bt) acc[mt][bt] = (f32x4){0.f, 0.f, 0.f, 0.f};

    __syncthreads();   // drains the 16 staging loads (vmcnt(0) at barrier)

#pragma unroll
    for (int s = 0; s < 16; ++s) {
        bf16x8 af[4];
#pragma unroll
        for (int mt = 0; mt < 4; ++mt)
            af[mt] = ldg8(arow + (size_t)mt * 16 * 512 + s * 32);
        bf16x8 bfr[2];
#pragma unroll
        for (int bt = 0; bt < 2; ++bt) {
            int t = wn * 32 + bt * 16 + lm;
            int c = s * 4 + quad;
            bfr[bt] = *(const bf16x8*)((const char*)Bl + t * 1024 + ((c ^ (t & 7)) << 4));
        }
#pragma unroll
        for (int mt = 0; mt < 4; ++mt)
#pragma unroll
            for (int bt = 0; bt < 2; ++bt)
                acc[mt][bt] = MFMA16(af[mt], bfr[bt], acc[mt][bt]);
    }

    const int mat = my >> 2;                        // 0=Q, 1=K, 2=V
    const float* bias = (mat == 0) ? qb : (mat == 1) ? kb : vb;
    const int chbase = (my & 3) * 128 + wm * 64 + quad * 4;

    if (mat < 2) {
        u16* out = mat ? Kt : Qt;
        const float sc = mat ? 1.0f : 0.125f * LOG2E;
#pragma unroll
        for (int mt = 0; mt < 4; ++mt) {
            const int ch = chbase + mt * 16;
            float4 bv = *(const float4*)(bias + ch);
            float bvf[4] = {bv.x, bv.y, bv.z, bv.w};
#pragma unroll
            for (int bt = 0; bt < 2; ++bt) {
                int tok = n0 + wn * 32 + bt * 16 + lm;
                u16x4 pk;
#pragma unroll
                for (int r = 0; r < 4; ++r)
                    pk[r] = f2bf((acc[mt][bt][r] + bvf[r]) * sc);
                *(u16x4*)(out + (size_t)tok * 512 + ch) = pk;
            }
        }
    } else {
#pragma unroll
        for (int mt = 0; mt < 4; ++mt) {
            const int ch = chbase + mt * 16;
            float4 bv = *(const float4*)(bias + ch);
            float bvf[4] = {bv.x, bv.y, bv.z, bv.w};
#pragma unroll
            for (int bt = 0; bt < 2; ++bt) {
                int g = bt * 16 + lm;
                int col = n0 + wn * 32 + 8 * ((g >> 2) & 3) + 4 * ((g >> 4) & 1) + (g & 3);
#pragma unroll
                for (int r = 0; r < 4; ++r)
                    Vp[(size_t)(ch + r) * 4096 + col] = f2bf(acc[mt][bt][r] + bvf[r]);
            }
        }
    }
}

// ---------------------------------------------------------------------------
// Output projection, BARRIER-FREE K-loop (same structure). Tile 64 x 64,
// B = Ot tile (64 KB) staged once, A = Wp streamed from global.
// Grid (64,8) = 512 blocks. fp32 channel-major output.
// ---------------------------------------------------------------------------
__global__ __launch_bounds__(256, 2) void out_gemm(const u16* __restrict__ Wp,
                                                   const u16* __restrict__ Ot,
                                                   const float* __restrict__ pb,
                                                   float* __restrict__ out) {
    __shared__ __align__(16) u16 Bl[64 * 512];      // 64 KB

    const int tid = threadIdx.x;
    const int w = tid >> 6, lane = tid & 63;
    const int quad = lane >> 4, lm = lane & 15;
    const int wm = w & 1, wn = w >> 1;
    const int n0 = blockIdx.x * 64;
    const int m0 = blockIdx.y * 64;

#pragma unroll
    for (int j = 0; j < 16; ++j) {
        int r = w + j * 4;
        async16(Ot + (size_t)(n0 + r) * 512 + (lane ^ (r & 7)) * 8,
                (char*)Bl + r * 1024);
    }

    const u16* arow = Wp + (size_t)(m0 + wm * 32 + lm) * 512 + quad * 8;

    f32x4 acc[2][2];
#pragma unroll
    for (int mt = 0; mt < 2; ++mt)
#pragma unroll
        for (int bt = 0; bt < 2; ++bt) acc[mt][bt] = (f32x4){0.f, 0.f, 0.f, 0.f};

    __syncthreads();

#pragma unroll
    for (int s = 0; s < 16; ++s) {
        bf16x8 af[2];
#pragma unroll
        for (int mt = 0; mt < 2; ++mt)
            af[mt] = ldg8(arow + (size_t)mt * 16 * 512 + s * 32);
        bf16x8 bfr[2];
#pragma unroll
        for (int bt = 0; bt < 2; ++bt) {
            int t = wn * 32 + bt * 16 + lm;
            int c = s * 4 + quad;
            bfr[bt] = *(const bf16x8*)((const char*)Bl + t * 1024 + ((c ^ (t & 7)) << 4));
        }
#pragma unroll
        for (int mt = 0; mt < 2; ++mt)
#pragma unroll
            for (int bt = 0; bt < 2; ++bt)
                acc[mt][bt] = MFMA16(af[mt], bfr[bt], acc[mt][bt]);
    }

#pragma unroll
    for (int mt = 0; mt < 2; ++mt) {
        const int ch = m0 + wm * 32 + mt * 16 + quad * 4;
        float4 bv = *(const float4*)(pb + ch);
        float bvf[4] = {bv.x, bv.y, bv.z, bv.w};
#pragma unroll
        for (int bt = 0; bt < 2; ++bt) {
            int tok = n0 + wn * 32 + bt * 16 + lm;
#pragma unroll
            for (int r = 0; r < 4; ++r)
                out[(size_t)(ch + r) * 4096 + tok] = acc[mt][bt][r] + bvf[r];
        }
    }
}

// ---------------------------------------------------------------------------
// Flash attention: round-13 proven version (52.9 us). 64-query blocks,
// 512 threads (8 waves), in-block split-K=2, max-free softmax, l via
// ones-row MFMA, stride-68 padded pure-add merge. (Round-14's 128-query
// variant regressed: doubling the barrier domain to 16 waves cost more
// than the staging traffic it saved.)
// ---------------------------------------------------------------------------
__global__ __launch_bounds__(512, 2) void flash_attn(const u16* __restrict__ Qt,
                                                     const u16* __restrict__ Kt,
                                                     const u16* __restrict__ Vp,
                                                     const float* __restrict__ lqw2g,
                                                     u16* __restrict__ Ot) {
    __shared__ __align__(16) u16 kv[2][2][2][4096];  // [half][buf][K|V] 8 KB each

    const int tid = threadIdx.x;
    const int w = tid >> 6, lane = tid & 63;         // w = 0..7
    const int quad = lane >> 4, lm = lane & 15;
    const int qw = w & 3, half = w >> 2;
    const int h = blockIdx.y, hq = h * 64;
    const int q0 = blockIdx.x * 64 + qw * 16;
    const int kstart = half * 2048;

    char* kvb = (char*)&kv[0][0][0][0] + half * 32768;
    const int srow = lane >> 3;
    const int schunk = (lane & 7) ^ srow;
    const u16* kgp = Kt + (size_t)(kstart + qw * 16 + srow) * 512 + hq + schunk * 8;
    const u16* kgp8 = kgp + (size_t)8 * 512;
    const u16* vgp = Vp + (size_t)(hq + qw * 16 + srow) * 4096 + kstart + schunk * 8;
    const u16* vgp8 = vgp + (size_t)8 * 4096;

    {
        char* nb = kvb + qw * 2048;
        async16(kgp, nb);        async16(kgp8, nb + 1024);
        async16(vgp, nb + 8192); async16(vgp8, nb + 8192 + 1024);
        kgp += 64 * 512; kgp8 += 64 * 512; vgp += 64; vgp8 += 64;
    }

    const int A0 = lm * 128 + (((quad ^ (lm & 3)) + 4 * ((lm >> 2) & 1)) << 4);
    const int A1 = A0 ^ 64;

    const u16* qbase = Qt + (size_t)(q0 + lm) * 512 + hq + quad * 8;
    const bf16x8 bq0 = ldg8(qbase);
    const bf16x8 bq1 = ldg8(qbase + 32);

    union { u32 u[4]; bf16x8 v; } onesu;
    onesu.u[0] = onesu.u[1] = onesu.u[2] = onesu.u[3] = 0x3F803F80u;
    const bf16x8 onesv = onesu.v;

    f32x4 acc_o[4];
#pragma unroll
    for (int mt = 0; mt < 4; ++mt) acc_o[mt] = (f32x4){0.f, 0.f, 0.f, 0.f};
    f32x4 acc_l = (f32x4){0.f, 0.f, 0.f, 0.f};

    __syncthreads();

#define ATTN_STEP(BUF, KT0, DO_STAGE)                                          \
    {                                                                          \
        if (DO_STAGE) {                                                        \
            char* nb = kvb + (((BUF) ^ 1) * 16384) + qw * 2048;                \
            async16(kgp, nb);        async16(kgp8, nb + 1024);                 \
            async16(vgp, nb + 8192); async16(vgp8, nb + 8192 + 1024);          \
            kgp += 64 * 512; kgp8 += 64 * 512; vgp += 64; vgp8 += 64;          \
        }                                                                      \
        const char* Kb = kvb + (BUF) * 16384;                                  \
        u32 pk[4][2];                                                          \
        _Pragma("unroll")                                                      \
        for (int nt = 0; nt < 4; ++nt) {                                       \
            bf16x8 k0 = *(const bf16x8*)(Kb + nt * 2048 + A0);                 \
            bf16x8 k1 = *(const bf16x8*)(Kb + nt * 2048 + A1);                 \
            f32x4 a = *(const f32x4*)(lqw2g + (KT0) + nt * 16 + quad * 4);     \
            a = MFMA16(k0, bq0, a);                                            \
            a = MFMA16(k1, bq1, a);                                            \
            float p0 = EXP2F(a[0]);                                            \
            float p1 = EXP2F(a[1]);                                            \
            float p2 = EXP2F(a[2]);                                            \
            float p3 = EXP2F(a[3]);                                            \
            pk[nt][0] = pack2(p0, p1);                                         \
            pk[nt][1] = pack2(p2, p3);                                         \
        }                                                                      \
        const char* Vb = kvb + (BUF) * 16384 + 8192;                           \
        _Pragma("unroll")                                                      \
        for (int kc = 0; kc < 2; ++kc) {                                       \
            union { u32 u[4]; bf16x8 v; } bb;                                  \
            bb.u[0] = pk[2 * kc][0];                                           \
            bb.u[1] = pk[2 * kc][1];                                           \
            bb.u[2] = pk[2 * kc + 1][0];                                       \
            bb.u[3] = pk[2 * kc + 1][1];                                       \
            const int Ax = kc ? A1 : A0;                                       \
            _Pragma("unroll")                                                  \
            for (int mt = 0; mt < 4; ++mt) {                                   \
                bf16x8 vv = *(const bf16x8*)(Vb + mt * 2048 + Ax);             \
                acc_o[mt] = MFMA16(vv, bb.v, acc_o[mt]);                       \
            }                                                                  \
            acc_l = MFMA16(onesv, bb.v, acc_l);                                \
        }                                                                      \
        __syncthreads();                                                       \
    }

    for (int kt0 = kstart; kt0 < kstart + 2048; kt0 += 128) {
        ATTN_STEP(0, kt0, true)
        ATTN_STEP(1, kt0 + 64, (kt0 + 128 < kstart + 2048))
    }
#undef ATTN_STEP

    // split-K merge: pure add (max-free). Padded stride 68 floats (bank-clean).
    float* mbuf = (float*)&kv[0][0][0][0];
    if (half == 1) {
        float* ob = mbuf + qw * 1088;
#pragma unroll
        for (int mt = 0; mt < 4; ++mt)
            *(f32x4*)(ob + lm * 68 + mt * 16 + quad * 4) = acc_o[mt];
        if (quad == 0) mbuf[4352 + qw * 16 + lm] = acc_l[0];
    }
    __syncthreads();
    if (half == 1) return;

    float* ob = mbuf + qw * 1088;
    float inv = 1.0f / (acc_l[0] + mbuf[4352 + qw * 16 + lm]);
#pragma unroll
    for (int mt = 0; mt < 4; ++mt) {
        f32x4 o1 = *(const f32x4*)(ob + lm * 68 + mt * 16 + quad * 4);
        u16x4 pkv;
#pragma unroll
        for (int r = 0; r < 4; ++r)
            pkv[r] = f2bf((acc_o[mt][r] + o1[r]) * inv);
        *reinterpret_cast<u16x4*>(Ot + (size_t)(q0 + lm) * 512 + hq + mt * 16 + quad * 4) = pkv;
    }
}

// ---------------------------------------------------------------------------
extern "C" void kernel_launch(void* const* d_in, const int* in_sizes, int n_in,
                              void* d_out, int out_size, void* d_ws, size_t ws_size,
                              hipStream_t stream) {
    (void)in_sizes; (void)n_in; (void)out_size; (void)ws_size;
    const float* X   = (const float*)d_in[0];
    const float* qw  = (const float*)d_in[1];
    const float* qb  = (const float*)d_in[2];
    const float* kw  = (const float*)d_in[3];
    const float* kb  = (const float*)d_in[4];
    const float* vw  = (const float*)d_in[5];
    const float* vb  = (const float*)d_in[6];
    const float* pw  = (const float*)d_in[7];
    const float* pb  = (const float*)d_in[8];
    const float* lqw = (const float*)d_in[9];

    const size_t E = (size_t)4096 * 512;
    const size_t WE = (size_t)512 * 512;
    u16* Xt    = (u16*)d_ws;
    u16* Qt    = Xt + E;
    u16* Kt    = Qt + E;
    u16* Vp    = Kt + E;
    u16* Wqkv  = Vp + E;          // 1536 x 512 stacked
    u16* Wp    = Wqkv + 3 * WE;
    float* lqw2g = (float*)(Wp + WE);   // 4096 fp32
    u16* Ot    = Xt;              // reuse (dead after qkv)

    prep<<<dim3(64, 13), dim3(256), 0, stream>>>(X, Xt, qw, kw, vw, pw,
                                                 Wqkv, Wp, lqw, lqw2g);
    qkv_gemm<<<dim3(64, 12), dim3(256), 0, stream>>>(Wqkv, Xt, qb, kb, vb, Qt, Kt, Vp);
    flash_attn<<<dim3(64, 8), dim3(512), 0, stream>>>(Qt, Kt, Vp, lqw2g, Ot);
    out_gemm<<<dim3(64, 8), dim3(256), 0, stream>>>(Wp, Ot, pb, (float*)d_out);
}

// Round 16
// 151.888 us; speedup vs baseline: 1.0865x; 1.0865x over previous
//
#include <hip/hip_runtime.h>

typedef unsigned short u16;
typedef unsigned int u32;
typedef __bf16 bf16x8 __attribute__((ext_vector_type(8)));
typedef float f32x4 __attribute__((ext_vector_type(4)));
typedef unsigned short u16x4 __attribute__((ext_vector_type(4)));

#define LOG2E 1.4426950408889634f

#if __has_builtin(__builtin_amdgcn_exp2f)
#define EXP2F(x) __builtin_amdgcn_exp2f(x)
#else
#define EXP2F(x) exp2f(x)
#endif

__device__ __forceinline__ u16 f2bf(float f) {
    union { float f; u32 u; } a; a.f = f;
    u32 u = a.u;
    u += 0x7FFFu + ((u >> 16) & 1u);   // RNE (finite inputs)
    return (u16)(u >> 16);
}
__device__ __forceinline__ bf16x8 ldg8(const u16* p) {
    return *reinterpret_cast<const bf16x8*>(p);
}
#if __has_builtin(__builtin_amdgcn_cvt_pk_bf16_f32)
__device__ __forceinline__ u32 pack2(float a, float b) {
    auto r = __builtin_amdgcn_cvt_pk_bf16_f32(a, b);
    return __builtin_bit_cast(u32, r);
}
#else
__device__ __forceinline__ u32 pack2(float a, float b) {
    u32 ua = __float_as_uint(a) + 0x8000u;
    u32 ub = __float_as_uint(b) + 0x8000u;
    return __builtin_amdgcn_perm(ub, ua, 0x07060302);
}
#endif
__device__ __forceinline__ void async16(const void* g, void* l) {
    __builtin_amdgcn_global_load_lds(
        (const __attribute__((address_space(1))) u32*)g,
        (__attribute__((address_space(3))) u32*)l, 16, 0, 0);
}

#define MFMA16(a, b, c) __builtin_amdgcn_mfma_f32_16x16x32_bf16((a), (b), (c), 0, 0, 0)

// ---------------------------------------------------------------------------
// Fused prep: y<8 -> transpose X tile; y in 8..11 -> pack weight matrix;
// y==12 -> lqw * log2(e) into global fp32 (4 blocks). Grid (64, 13).
// ---------------------------------------------------------------------------
__global__ __launch_bounds__(256) void prep(const float* __restrict__ X,
                                            u16* __restrict__ Xt,
                                            const float* __restrict__ s0,
                                            const float* __restrict__ s1,
                                            const float* __restrict__ s2,
                                            const float* __restrict__ s3,
                                            u16* __restrict__ Wqkv,
                                            u16* __restrict__ Wp,
                                            const float* __restrict__ lqw,
                                            float* __restrict__ lqw2g) {
    __shared__ u16 tile[64][65];
    const int tid = threadIdx.x;
    const int y = blockIdx.y;

    if (y < 8) {                                  // transpose 64x64 tile
        const int t0 = blockIdx.x * 64;
        const int c0 = y * 64;
#pragma unroll
        for (int i = 0; i < 16; ++i) {
            int idx = tid + i * 256;
            int r = idx >> 6, cc = idx & 63;
            tile[r][cc] = f2bf(X[(size_t)(c0 + r) * 4096 + t0 + cc]);
        }
        __syncthreads();
#pragma unroll
        for (int i = 0; i < 16; ++i) {
            int idx = tid + i * 256;
            int tr = idx >> 6, cc = idx & 63;
            Xt[(size_t)(t0 + tr) * 512 + c0 + cc] = tile[cc][tr];
        }
    } else if (y < 12) {                          // pack one 512x512 weight
        const int m = y - 8;
        const float* s = (m == 0) ? s0 : (m == 1) ? s1 : (m == 2) ? s2 : s3;
        u16* d = (m == 3) ? Wp : Wqkv + (size_t)m * 262144;
#pragma unroll
        for (int j = 0; j < 4; ++j) {
            int i = blockIdx.x * 1024 + j * 256 + tid;
            float4 v = reinterpret_cast<const float4*>(s)[i];
            u16x4 o;
            o[0] = f2bf(v.x); o[1] = f2bf(v.y); o[2] = f2bf(v.z); o[3] = f2bf(v.w);
            reinterpret_cast<u16x4*>(d)[i] = o;
        }
    } else {                                      // lqw * LOG2E (1024 float4)
        if (blockIdx.x < 4) {
            int i = blockIdx.x * 256 + tid;
            float4 v = reinterpret_cast<const float4*>(lqw)[i];
            v.x *= LOG2E; v.y *= LOG2E; v.z *= LOG2E; v.w *= LOG2E;
            reinterpret_cast<float4*>(lqw2g)[i] = v;
        }
    }
}

// ---------------------------------------------------------------------------
// Fused QKV GEMM (round-13 proven): 256-thread blocks, tile 128(M) x 64(N),
// BK=32 double-buffered global_load_lds. Grid (64,12) = 768 blocks, ~3/CU.
// ---------------------------------------------------------------------------
__global__ __launch_bounds__(256, 4) void qkv_gemm(const u16* __restrict__ Wqkv,
                                                   const u16* __restrict__ Xt,
                                                   const float* __restrict__ qb,
                                                   const float* __restrict__ kb,
                                                   const float* __restrict__ vb,
                                                   u16* __restrict__ Qt,
                                                   u16* __restrict__ Kt,
                                                   u16* __restrict__ Vp) {
    __shared__ __align__(16) u16 Al[2][128 * 32];   // 2 x 8 KB
    __shared__ __align__(16) u16 Bl[2][64 * 32];    // 2 x 4 KB

    const int tid = threadIdx.x;
    const int w = tid >> 6, lane = tid & 63;
    const int quad = lane >> 4, lm = lane & 15;
    const int wm = w & 1, wn = w >> 1;
    const int n0 = blockIdx.x * 64;
    const int my = blockIdx.y;                      // 0..11 over M=1536
    const int m0 = my * 128;

    const int arow = lane >> 2;
    const int sch = (lane & 3) ^ ((lane >> 3) & 3);
    const u16* agp0 = Wqkv + (size_t)(m0 + w * 32 + arow) * 512 + sch * 8;
    const u16* agp1 = agp0 + (size_t)16 * 512;
    const u16* bgp = Xt + (size_t)(n0 + w * 16 + arow) * 512 + sch * 8;

    async16(agp0, &Al[0][w * 32 * 32]);
    async16(agp1, &Al[0][(w * 32 + 16) * 32]);
    async16(bgp, &Bl[0][w * 16 * 32]);
    agp0 += 32; agp1 += 32; bgp += 32;

    const int FOFF = lm * 64 + ((quad ^ ((lm >> 1) & 3)) << 4);

    f32x4 acc[4][2];
#pragma unroll
    for (int mt = 0; mt < 4; ++mt)
#pragma unroll
        for (int bt = 0; bt < 2; ++bt) acc[mt][bt] = (f32x4){0.f, 0.f, 0.f, 0.f};

    __syncthreads();

    for (int s = 0; s < 16; ++s) {
        const int buf = s & 1;
        if (s < 15) {
            async16(agp0, &Al[buf ^ 1][w * 32 * 32]);
            async16(agp1, &Al[buf ^ 1][(w * 32 + 16) * 32]);
            async16(bgp, &Bl[buf ^ 1][w * 16 * 32]);
            agp0 += 32; agp1 += 32; bgp += 32;
        }
        const char* Ab = (const char*)&Al[buf][0];
        const char* Bb = (const char*)&Bl[buf][0];
        bf16x8 af[4], bfr[2];
#pragma unroll
        for (int mt = 0; mt < 4; ++mt)
            af[mt] = *(const bf16x8*)(Ab + wm * 4096 + mt * 1024 + FOFF);
#pragma unroll
        for (int bt = 0; bt < 2; ++bt)
            bfr[bt] = *(const bf16x8*)(Bb + wn * 2048 + bt * 1024 + FOFF);
#pragma unroll
        for (int mt = 0; mt < 4; ++mt)
#pragma unroll
            for (int bt = 0; bt < 2; ++bt)
                acc[mt][bt] = MFMA16(af[mt], bfr[bt], acc[mt][bt]);
        __syncthreads();
    }

    const int mat = my >> 2;                        // 0=Q, 1=K, 2=V
    const float* bias = (mat == 0) ? qb : (mat == 1) ? kb : vb;
    const int chbase = (my & 3) * 128 + wm * 64 + quad * 4;

    if (mat < 2) {
        u16* out = mat ? Kt : Qt;
        const float sc = mat ? 1.0f : 0.125f * LOG2E;
#pragma unroll
        for (int mt = 0; mt < 4; ++mt) {
            const int ch = chbase + mt * 16;
            float4 bv = *(const float4*)(bias + ch);
            float bvf[4] = {bv.x, bv.y, bv.z, bv.w};
#pragma unroll
            for (int bt = 0; bt < 2; ++bt) {
                int tok = n0 + wn * 32 + bt * 16 + lm;
                u16x4 pk;
#pragma unroll
                for (int r = 0; r < 4; ++r)
                    pk[r] = f2bf((acc[mt][bt][r] + bvf[r]) * sc);
                *(u16x4*)(out + (size_t)tok * 512 + ch) = pk;
            }
        }
    } else {
#pragma unroll
        for (int mt = 0; mt < 4; ++mt) {
            const int ch = chbase + mt * 16;
            float4 bv = *(const float4*)(bias + ch);
            float bvf[4] = {bv.x, bv.y, bv.z, bv.w};
#pragma unroll
            for (int bt = 0; bt < 2; ++bt) {
                int g = bt * 16 + lm;
                int col = n0 + wn * 32 + 8 * ((g >> 2) & 3) + 4 * ((g >> 4) & 1) + (g & 3);
#pragma unroll
                for (int r = 0; r < 4; ++r)
                    Vp[(size_t)(ch + r) * 4096 + col] = f2bf(acc[mt][bt][r] + bvf[r]);
            }
        }
    }
}

// ---------------------------------------------------------------------------
// Output projection (round-13 proven): 256-thread blocks, tile 64 x 64,
// BK=32. Grid (64,8) = 512 blocks = 2/CU.
// ---------------------------------------------------------------------------
__global__ __launch_bounds__(256, 4) void out_gemm(const u16* __restrict__ Wp,
                                                   const u16* __restrict__ Ot,
                                                   const float* __restrict__ pb,
                                                   float* __restrict__ out) {
    __shared__ __align__(16) u16 Al[2][64 * 32];    // 2 x 4 KB
    __shared__ __align__(16) u16 Bl[2][64 * 32];    // 2 x 4 KB

    const int tid = threadIdx.x;
    const int w = tid >> 6, lane = tid & 63;
    const int quad = lane >> 4, lm = lane & 15;
    const int wm = w & 1, wn = w >> 1;
    const int n0 = blockIdx.x * 64;
    const int m0 = blockIdx.y * 64;

    const int arow = lane >> 2;
    const int sch = (lane & 3) ^ ((lane >> 3) & 3);
    const u16* agp = Wp + (size_t)(m0 + w * 16 + arow) * 512 + sch * 8;
    const u16* bgp = Ot + (size_t)(n0 + w * 16 + arow) * 512 + sch * 8;

    async16(agp, &Al[0][w * 16 * 32]);
    async16(bgp, &Bl[0][w * 16 * 32]);
    agp += 32; bgp += 32;

    const int FOFF = lm * 64 + ((quad ^ ((lm >> 1) & 3)) << 4);

    f32x4 acc[2][2];
#pragma unroll
    for (int mt = 0; mt < 2; ++mt)
#pragma unroll
        for (int bt = 0; bt < 2; ++bt) acc[mt][bt] = (f32x4){0.f, 0.f, 0.f, 0.f};

    __syncthreads();

    for (int s = 0; s < 16; ++s) {
        const int buf = s & 1;
        if (s < 15) {
            async16(agp, &Al[buf ^ 1][w * 16 * 32]);
            async16(bgp, &Bl[buf ^ 1][w * 16 * 32]);
            agp += 32; bgp += 32;
        }
        const char* Ab = (const char*)&Al[buf][0];
        const char* Bb = (const char*)&Bl[buf][0];
        bf16x8 af[2], bfr[2];
#pragma unroll
        for (int mt = 0; mt < 2; ++mt)
            af[mt] = *(const bf16x8*)(Ab + wm * 2048 + mt * 1024 + FOFF);
#pragma unroll
        for (int bt = 0; bt < 2; ++bt)
            bfr[bt] = *(const bf16x8*)(Bb + wn * 2048 + bt * 1024 + FOFF);
#pragma unroll
        for (int mt = 0; mt < 2; ++mt)
#pragma unroll
            for (int bt = 0; bt < 2; ++bt)
                acc[mt][bt] = MFMA16(af[mt], bfr[bt], acc[mt][bt]);
        __syncthreads();
    }

#pragma unroll
    for (int mt = 0; mt < 2; ++mt) {
        const int ch = m0 + wm * 32 + mt * 16 + quad * 4;
        float4 bv = *(const float4*)(pb + ch);
        float bvf[4] = {bv.x, bv.y, bv.z, bv.w};
#pragma unroll
        for (int bt = 0; bt < 2; ++bt) {
            int tok = n0 + wn * 32 + bt * 16 + lm;
#pragma unroll
            for (int r = 0; r < 4; ++r)
                out[(size_t)(ch + r) * 4096 + tok] = acc[mt][bt][r] + bvf[r];
        }
    }
}

// ---------------------------------------------------------------------------
// Flash attention (round-13 base, 52.9 us) + two tweaks:
// (1) fully unrolled K-loop (constant trip count 16): LDS/lqw2g offsets are
//     base+immediate; the independent lqw2g C-init loads can be hoisted and
//     issued iterations ahead by the scheduler.
// (2) XCD-aware head swizzle: grid flattened to 1D, h = blockIdx.x & 7 —
//     blocks round-robin across the 8 XCDs, so each XCD concentrates on one
//     head (8 MB K/V vs 64 MB for all heads) -> better L2 hit, less drain.
// 64-query blocks, 512 threads (8 waves), in-block split-K=2, max-free
// softmax, l via ones-row MFMA, stride-68 padded pure-add merge.
// ---------------------------------------------------------------------------
__global__ __launch_bounds__(512, 2) void flash_attn(const u16* __restrict__ Qt,
                                                     const u16* __restrict__ Kt,
                                                     const u16* __restrict__ Vp,
                                                     const float* __restrict__ lqw2g,
                                                     u16* __restrict__ Ot) {
    __shared__ __align__(16) u16 kv[2][2][2][4096];  // [half][buf][K|V] 8 KB each

    const int tid = threadIdx.x;
    const int w = tid >> 6, lane = tid & 63;         // w = 0..7
    const int quad = lane >> 4, lm = lane & 15;
    const int qw = w & 3, half = w >> 2;
    const int h = blockIdx.x & 7;                    // XCD-aware: XCD j ~ head j
    const int hq = h * 64;
    const int q0 = (blockIdx.x >> 3) * 64 + qw * 16;
    const int kstart = half * 2048;

    char* kvb = (char*)&kv[0][0][0][0] + half * 32768;
    const int srow = lane >> 3;
    const int schunk = (lane & 7) ^ srow;
    const u16* kgp = Kt + (size_t)(kstart + qw * 16 + srow) * 512 + hq + schunk * 8;
    const u16* kgp8 = kgp + (size_t)8 * 512;
    const u16* vgp = Vp + (size_t)(hq + qw * 16 + srow) * 4096 + kstart + schunk * 8;
    const u16* vgp8 = vgp + (size_t)8 * 4096;

    {
        char* nb = kvb + qw * 2048;
        async16(kgp, nb);        async16(kgp8, nb + 1024);
        async16(vgp, nb + 8192); async16(vgp8, nb + 8192 + 1024);
        kgp += 64 * 512; kgp8 += 64 * 512; vgp += 64; vgp8 += 64;
    }

    const int A0 = lm * 128 + (((quad ^ (lm & 3)) + 4 * ((lm >> 2) & 1)) << 4);
    const int A1 = A0 ^ 64;

    const u16* qbase = Qt + (size_t)(q0 + lm) * 512 + hq + quad * 8;
    const bf16x8 bq0 = ldg8(qbase);
    const bf16x8 bq1 = ldg8(qbase + 32);

    union { u32 u[4]; bf16x8 v; } onesu;
    onesu.u[0] = onesu.u[1] = onesu.u[2] = onesu.u[3] = 0x3F803F80u;
    const bf16x8 onesv = onesu.v;

    f32x4 acc_o[4];
#pragma unroll
    for (int mt = 0; mt < 4; ++mt) acc_o[mt] = (f32x4){0.f, 0.f, 0.f, 0.f};
    f32x4 acc_l = (f32x4){0.f, 0.f, 0.f, 0.f};

    const float* lqbase = lqw2g + kstart;            // wave-half bias base

    __syncthreads();

#define ATTN_STEP(BUF, KOFF, DO_STAGE)                                         \
    {                                                                          \
        if (DO_STAGE) {                                                        \
            char* nb = kvb + (((BUF) ^ 1) * 16384) + qw * 2048;                \
            async16(kgp, nb);        async16(kgp8, nb + 1024);                 \
            async16(vgp, nb + 8192); async16(vgp8, nb + 8192 + 1024);          \
            kgp += 64 * 512; kgp8 += 64 * 512; vgp += 64; vgp8 += 64;          \
        }                                                                      \
        const char* Kb = kvb + (BUF) * 16384;                                  \
        u32 pk[4][2];                                                          \
        _Pragma("unroll")                                                      \
        for (int nt = 0; nt < 4; ++nt) {                                       \
            bf16x8 k0 = *(const bf16x8*)(Kb + nt * 2048 + A0);                 \
            bf16x8 k1 = *(const bf16x8*)(Kb + nt * 2048 + A1);                 \
            f32x4 a = *(const f32x4*)(lqbase + (KOFF) + nt * 16 + quad * 4);   \
            a = MFMA16(k0, bq0, a);                                            \
            a = MFMA16(k1, bq1, a);                                            \
            float p0 = EXP2F(a[0]);                                            \
            float p1 = EXP2F(a[1]);                                            \
            float p2 = EXP2F(a[2]);                                            \
            float p3 = EXP2F(a[3]);                                            \
            pk[nt][0] = pack2(p0, p1);                                         \
            pk[nt][1] = pack2(p2, p3);                                         \
        }                                                                      \
        const char* Vb = kvb + (BUF) * 16384 + 8192;                           \
        _Pragma("unroll")                                                      \
        for (int kc = 0; kc < 2; ++kc) {                                       \
            union { u32 u[4]; bf16x8 v; } bb;                                  \
            bb.u[0] = pk[2 * kc][0];                                           \
            bb.u[1] = pk[2 * kc][1];                                           \
            bb.u[2] = pk[2 * kc + 1][0];                                       \
            bb.u[3] = pk[2 * kc + 1][1];                                       \
            const int Ax = kc ? A1 : A0;                                       \
            _Pragma("unroll")                                                  \
            for (int mt = 0; mt < 4; ++mt) {                                   \
                bf16x8 vv = *(const bf16x8*)(Vb + mt * 2048 + Ax);             \
                acc_o[mt] = MFMA16(vv, bb.v, acc_o[mt]);                       \
            }                                                                  \
            acc_l = MFMA16(onesv, bb.v, acc_l);                                \
        }                                                                      \
        __syncthreads();                                                       \
    }

#pragma unroll
    for (int i = 0; i < 16; ++i) {                   // constant trip count
        ATTN_STEP(0, i * 128, true)
        ATTN_STEP(1, i * 128 + 64, (i < 15))
    }
#undef ATTN_STEP

    // split-K merge: pure add (max-free). Padded stride 68 floats (bank-clean).
    float* mbuf = (float*)&kv[0][0][0][0];
    if (half == 1) {
        float* ob = mbuf + qw * 1088;
#pragma unroll
        for (int mt = 0; mt < 4; ++mt)
            *(f32x4*)(ob + lm * 68 + mt * 16 + quad * 4) = acc_o[mt];
        if (quad == 0) mbuf[4352 + qw * 16 + lm] = acc_l[0];
    }
    __syncthreads();
    if (half == 1) return;

    float* ob = mbuf + qw * 1088;
    float inv = 1.0f / (acc_l[0] + mbuf[4352 + qw * 16 + lm]);
#pragma unroll
    for (int mt = 0; mt < 4; ++mt) {
        f32x4 o1 = *(const f32x4*)(ob + lm * 68 + mt * 16 + quad * 4);
        u16x4 pkv;
#pragma unroll
        for (int r = 0; r < 4; ++r)
            pkv[r] = f2bf((acc_o[mt][r] + o1[r]) * inv);
        *reinterpret_cast<u16x4*>(Ot + (size_t)(q0 + lm) * 512 + hq + mt * 16 + quad * 4) = pkv;
    }
}

// ---------------------------------------------------------------------------
extern "C" void kernel_launch(void* const* d_in, const int* in_sizes, int n_in,
                              void* d_out, int out_size, void* d_ws, size_t ws_size,
                              hipStream_t stream) {
    (void)in_sizes; (void)n_in; (void)out_size; (void)ws_size;
    const float* X   = (const float*)d_in[0];
    const float* qw  = (const float*)d_in[1];
    const float* qb  = (const float*)d_in[2];
    const float* kw  = (const float*)d_in[3];
    const float* kb  = (const float*)d_in[4];
    const float* vw  = (const float*)d_in[5];
    const float* vb  = (const float*)d_in[6];
    const float* pw  = (const float*)d_in[7];
    const float* pb  = (const float*)d_in[8];
    const float* lqw = (const float*)d_in[9];

    const size_t E = (size_t)4096 * 512;
    const size_t WE = (size_t)512 * 512;
    u16* Xt    = (u16*)d_ws;
    u16* Qt    = Xt + E;
    u16* Kt    = Qt + E;
    u16* Vp    = Kt + E;
    u16* Wqkv  = Vp + E;          // 1536 x 512 stacked
    u16* Wp    = Wqkv + 3 * WE;
    float* lqw2g = (float*)(Wp + WE);   // 4096 fp32
    u16* Ot    = Xt;              // reuse (dead after qkv)

    prep<<<dim3(64, 13), dim3(256), 0, stream>>>(X, Xt, qw, kw, vw, pw,
                                                 Wqkv, Wp, lqw, lqw2g);
    qkv_gemm<<<dim3(64, 12), dim3(256), 0, stream>>>(Wqkv, Xt, qb, kb, vb, Qt, Kt, Vp);
    flash_attn<<<dim3(512), dim3(512), 0, stream>>>(Qt, Kt, Vp, lqw2g, Ot);
    out_gemm<<<dim3(64, 8), dim3(256), 0, stream>>>(Wp, Ot, pb, (float*)d_out);
}